// Round 2
// baseline (245.300 us; speedup 1.0000x reference)
//
#include <hip/hip_runtime.h>

// LengthRegulator: B=32, T=512, D=384, ML=4096 (fixed by setup_inputs).
// out[b,f,:] = (f < total_b) ? x[b, searchsorted(cum_b, f, 'right').clip(0,T-1), :] : 0
// mel_pos[b,f] = (f < total_b) ? f+1 : 0   (written as FLOAT values)
//
// V2b: two-kernel split (compile fix: nontemporal stores need a native clang
// vector type, not HIP's float4 class).
//   tok_kernel : 256 blocks, computes int16 token map into d_ws (256 KB).
//   copy_kernel: 1024 blocks, pure streaming gather; tok in LDS; nontemporal
//                16B stores; all-valid / all-invalid fast paths; XCD-affine
//                swizzle (batch b pinned to XCD b/4) so x + tok stay in one L2.
// Fallback to the previous single-kernel path if ws_size < 256 KB.

constexpr int B   = 32;
constexpr int T   = 512;
constexpr int D   = 384;
constexpr int ML  = 4096;
constexpr int D4  = D / 4;            // 96 vec4 per row
constexpr int NT  = 256;              // threads per block
constexpr int FPB = 128;              // frames per copy-block
constexpr int BLOCKS_PER_BATCH = ML / FPB;   // 32
constexpr int NXCD = 8;

typedef float f32x4 __attribute__((ext_vector_type(4)));

// ---------------------------------------------------------------------------
// Kernel 1: token map. grid = 256 blocks (8 XCD x 4 batches x 8 segments).
// blk&7 = xcd (assumed round-robin dispatch); batch b = xcd*4 + hi bits.
// ---------------------------------------------------------------------------
__global__ __launch_bounds__(NT) void tok_kernel(
        const int* __restrict__ dur,    // [B, T]
        short*     __restrict__ tok)    // [B, ML]
{
    __shared__ int s_cum[T];
    __shared__ int s_part[NT];

    const int blk = blockIdx.x;
    const int xcd = blk & (NXCD - 1);
    const int j   = blk >> 3;            // 0..31
    const int b   = xcd * 4 + (j >> 3);  // 4 batches per XCD
    const int seg = j & 7;               // 8 x 512-frame segments
    const int tid = threadIdx.x;

    // cumsum(duration[b]) into LDS (each thread owns 2 elements)
    const int d0 = dur[b * T + 2 * tid];
    const int d1 = dur[b * T + 2 * tid + 1];
    const int pair = d0 + d1;
    s_part[tid] = pair;
    __syncthreads();
    int val = pair;
    #pragma unroll
    for (int off = 1; off < NT; off <<= 1) {
        int t = (tid >= off) ? s_part[tid - off] : 0;
        __syncthreads();
        val += t;
        s_part[tid] = val;
        __syncthreads();
    }
    const int excl = val - pair;
    s_cum[2 * tid]     = excl + d0;
    s_cum[2 * tid + 1] = excl + pair;
    __syncthreads();
    const int total = s_cum[T - 1];

    // binary search for this block's 512 frames (2 per thread)
    #pragma unroll
    for (int k = 0; k < 2; ++k) {
        const int f = seg * 512 + k * NT + tid;
        int lo = 0, hi = T;              // searchsorted(side='right')
        while (lo < hi) {
            const int mid = (lo + hi) >> 1;
            if (s_cum[mid] <= f) lo = mid + 1; else hi = mid;
        }
        const int tk = (lo < T - 1) ? lo : (T - 1);
        tok[b * ML + f] = (f < total) ? (short)tk : (short)-1;
    }
}

// ---------------------------------------------------------------------------
// Kernel 2: streaming gather-copy. grid = 1024 blocks.
// blk&7 = xcd; batch b = xcd*4 + (j>>5) matches tok_kernel's mapping so the
// token map and x rows for batch b are already resident in that XCD's L2.
// ---------------------------------------------------------------------------
__global__ __launch_bounds__(NT) void copy_kernel(
        const f32x4*  __restrict__ x,     // [B, T, D4]
        const short*  __restrict__ tok,   // [B, ML]
        f32x4*        __restrict__ out4,  // [B, ML, D4]
        float*        __restrict__ mel)   // [B, ML]
{
    __shared__ short s_tok[FPB];

    const int blk = blockIdx.x;
    const int xcd = blk & (NXCD - 1);
    const int j   = blk >> 3;             // 0..127
    const int b   = xcd * 4 + (j >> 5);   // 4 batches per XCD
    const int fchunk = j & 31;            // 32 chunks per batch
    const int f0  = fchunk * FPB;
    const int tid = threadIdx.x;

    if (tid < FPB) {
        const short tk = tok[b * ML + f0 + tid];
        s_tok[tid] = tk;
        const float mv = (tk >= 0) ? (float)(f0 + tid + 1) : 0.0f;
        __builtin_nontemporal_store(mv, &mel[b * ML + f0 + tid]);
    }
    __syncthreads();

    const size_t out_base = ((size_t)b * ML + f0) * D4;
    const f32x4 zero4 = {0.f, 0.f, 0.f, 0.f};

    // tok is nondecreasing with a -1 tail: chunk-uniform classification.
    if (s_tok[0] < 0) {
        // entire chunk past total: pure zero-fill (fill-kernel rate)
        #pragma unroll 8
        for (int i = tid; i < FPB * D4; i += NT)
            __builtin_nontemporal_store(zero4, &out4[out_base + i]);
        return;
    }

    const size_t x_base = (size_t)b * T * D4;
    if (s_tok[FPB - 1] >= 0) {
        // entire chunk valid: unconditional gather
        #pragma unroll 4
        for (int i = tid; i < FPB * D4; i += NT) {
            const int lf = i / D4;
            const int c  = i - lf * D4;
            const f32x4 v = x[x_base + (size_t)s_tok[lf] * D4 + c];
            __builtin_nontemporal_store(v, &out4[out_base + i]);
        }
    } else {
        // mixed chunk (~1 per batch): general path
        #pragma unroll 4
        for (int i = tid; i < FPB * D4; i += NT) {
            const int lf = i / D4;
            const int c  = i - lf * D4;
            const int tk = s_tok[lf];
            f32x4 v = zero4;
            if (tk >= 0) v = x[x_base + (size_t)tk * D4 + c];
            __builtin_nontemporal_store(v, &out4[out_base + i]);
        }
    }
}

// ---------------------------------------------------------------------------
// Fallback: previous verified single-kernel path (used only if d_ws too small)
// ---------------------------------------------------------------------------
__global__ __launch_bounds__(NT) void lr_kernel(
        const float4* __restrict__ x,
        const int*    __restrict__ dur,
        float*        __restrict__ outf,
        float*        __restrict__ mel)
{
    __shared__ int s_cum[T];
    __shared__ int s_tok[FPB];
    __shared__ int s_part[NT];

    const int b      = blockIdx.x / BLOCKS_PER_BATCH;
    const int fchunk = blockIdx.x % BLOCKS_PER_BATCH;
    const int f0     = fchunk * FPB;
    const int tid    = threadIdx.x;

    const int d0 = dur[b * T + 2 * tid];
    const int d1 = dur[b * T + 2 * tid + 1];
    const int pair = d0 + d1;
    s_part[tid] = pair;
    __syncthreads();
    int val = pair;
    #pragma unroll
    for (int off = 1; off < NT; off <<= 1) {
        int t = (tid >= off) ? s_part[tid - off] : 0;
        __syncthreads();
        val += t;
        s_part[tid] = val;
        __syncthreads();
    }
    const int excl = val - pair;
    s_cum[2 * tid]     = excl + d0;
    s_cum[2 * tid + 1] = excl + pair;
    __syncthreads();
    const int total = s_cum[T - 1];

    if (tid < FPB) {
        const int f = f0 + tid;
        int lo = 0, hi = T;
        while (lo < hi) {
            const int mid = (lo + hi) >> 1;
            if (s_cum[mid] <= f) lo = mid + 1; else hi = mid;
        }
        const int tok = (lo < T - 1) ? lo : (T - 1);
        s_tok[tid] = (f < total) ? tok : -1;
        mel[b * ML + f] = (f < total) ? (float)(f + 1) : 0.0f;
    }
    __syncthreads();

    float4* __restrict__ out4 = (float4*)outf;
    const float4 zero4 = make_float4(0.f, 0.f, 0.f, 0.f);
    const size_t out_base = ((size_t)b * ML + f0) * D4;
    const size_t x_base   = (size_t)b * T * D4;
    #pragma unroll 4
    for (int i = tid; i < FPB * D4; i += NT) {
        const int lf  = i / D4;
        const int c   = i - lf * D4;
        const int tok = s_tok[lf];
        float4 v = zero4;
        if (tok >= 0) v = x[x_base + (size_t)tok * D4 + c];
        out4[out_base + (size_t)lf * D4 + c] = v;
    }
}

extern "C" void kernel_launch(void* const* d_in, const int* in_sizes, int n_in,
                              void* d_out, int out_size, void* d_ws, size_t ws_size,
                              hipStream_t stream) {
    const float*  xf  = (const float*)d_in[0];
    const int*    dur = (const int*)d_in[1];
    float* outf = (float*)d_out;
    float* mel  = outf + (size_t)B * ML * D;   // mel_pos region, float values

    const size_t tok_bytes = (size_t)B * ML * sizeof(short);   // 256 KB
    if (d_ws != nullptr && ws_size >= tok_bytes) {
        short* tok = (short*)d_ws;
        tok_kernel<<<dim3(256), dim3(NT), 0, stream>>>(dur, tok);
        copy_kernel<<<dim3(B * BLOCKS_PER_BATCH), dim3(NT), 0, stream>>>(
            (const f32x4*)xf, tok, (f32x4*)outf, mel);
    } else {
        lr_kernel<<<dim3(B * BLOCKS_PER_BATCH), dim3(NT), 0, stream>>>(
            (const float4*)xf, dur, outf, mel);
    }
}

// Round 3
// 229.733 us; speedup vs baseline: 1.0678x; 1.0678x over previous
//
#include <hip/hip_runtime.h>

// LengthRegulator: B=32, T=512, D=384, ML=4096 (fixed by setup_inputs).
// out[b,f,:] = (f < total_b) ? x[b, searchsorted(cum_b, f, 'right').clip(0,T-1), :] : 0
// mel_pos[b,f] = (f < total_b) ? f+1 : 0   (written as FLOAT values)
//
// V3: single kernel (one graph node — the V2 split cost ~10us in node overhead
// and gained nothing). Changes vs V1 (231.7us):
//   - FPB=64 -> grid 2048 blocks = 8 blocks/CU = 32 waves/CU (full occupancy;
//     V1/V2 ran at 50%). Tests the store-latency-hiding hypothesis.
//   - division-free addressing: thread -> (frame-group, col-group) via
//     shift/mask; one LDS tok read per 3 stores.
//   - nontemporal 16B stores (output is write-once, keep L2 for x).
//   - chunk-uniform fast paths (tok nondecreasing with -1 tail): pure
//     zero-fill / pure gather / mixed.

constexpr int B   = 32;
constexpr int T   = 512;
constexpr int D   = 384;
constexpr int ML  = 4096;
constexpr int D4  = D / 4;             // 96 vec4 per row
constexpr int NT  = 256;               // threads per block
constexpr int FPB = 64;                // frames per block
constexpr int CHUNKS = ML / FPB;       // 64 chunks per batch
constexpr int NVEC = FPB * D4;         // 6144 vec4 per block

typedef float f32x4 __attribute__((ext_vector_type(4)));

__global__ __launch_bounds__(NT) void lr_kernel(
        const f32x4* __restrict__ x,     // [B, T, D4]
        const int*   __restrict__ dur,   // [B, T]
        f32x4*       __restrict__ out4,  // [B, ML, D4]
        float*       __restrict__ mel)   // [B, ML]
{
    __shared__ int   s_cum[T];
    __shared__ int   s_part[NT];
    __shared__ short s_tok[FPB];

    const int blk    = blockIdx.x;
    const int b      = blk >> 6;          // 64 chunks per batch
    const int fchunk = blk & (CHUNKS - 1);
    const int f0     = fchunk * FPB;
    const int tid    = threadIdx.x;

    // ---- cumsum(duration[b]) into LDS (each thread owns 2 elements) ----
    const int d0 = dur[b * T + 2 * tid];
    const int d1 = dur[b * T + 2 * tid + 1];
    const int pair = d0 + d1;
    s_part[tid] = pair;
    __syncthreads();
    int val = pair;
    #pragma unroll
    for (int off = 1; off < NT; off <<= 1) {
        int t = (tid >= off) ? s_part[tid - off] : 0;
        __syncthreads();
        val += t;
        s_part[tid] = val;
        __syncthreads();
    }
    const int excl = val - pair;          // exclusive scan of pair-sums
    s_cum[2 * tid]     = excl + d0;
    s_cum[2 * tid + 1] = excl + pair;
    __syncthreads();
    const int total = s_cum[T - 1];

    // ---- token index for this block's FPB frames ----
    if (tid < FPB) {
        const int f = f0 + tid;
        int lo = 0, hi = T;               // searchsorted(side='right')
        while (lo < hi) {
            const int mid = (lo + hi) >> 1;
            if (s_cum[mid] <= f) lo = mid + 1; else hi = mid;
        }
        const int tk = (lo < T - 1) ? lo : (T - 1);
        s_tok[tid] = (f < total) ? (short)tk : (short)-1;
        const float mv = (f < total) ? (float)(f + 1) : 0.0f;
        __builtin_nontemporal_store(mv, &mel[b * ML + f]);
    }
    __syncthreads();

    const size_t out_base = ((size_t)b * ML + f0) * D4;
    const f32x4  zero4    = {0.f, 0.f, 0.f, 0.f};

    // tok is nondecreasing with a -1 tail: chunk-uniform classification.
    if (s_tok[FPB - 1] < 0) {
        if (s_tok[0] < 0) {
            // whole chunk past total: pure zero-fill, linear stream
            #pragma unroll
            for (int i = tid; i < NVEC; i += NT)
                __builtin_nontemporal_store(zero4, &out4[out_base + i]);
            return;
        }
        // mixed chunk (~1 per batch): per-frame validity
        const size_t x_base = (size_t)b * T * D4;
        const int c2 = tid & 31;          // col-group base (32 vec4)
        const int fg = tid >> 5;          // 8 parallel frames
        #pragma unroll
        for (int k = 0; k < FPB / 8; ++k) {
            const int lf = fg + (k << 3);
            const int tk = s_tok[lf];
            const size_t orow = out_base + (size_t)lf * D4;
            if (tk >= 0) {
                const size_t xrow = x_base + (size_t)tk * D4;
                #pragma unroll
                for (int j = 0; j < 3; ++j) {
                    const int c = c2 + (j << 5);
                    __builtin_nontemporal_store(x[xrow + c], &out4[orow + c]);
                }
            } else {
                #pragma unroll
                for (int j = 0; j < 3; ++j)
                    __builtin_nontemporal_store(zero4, &out4[orow + c2 + (j << 5)]);
            }
        }
        return;
    }

    // whole chunk valid: unconditional gather, division-free addressing
    {
        const size_t x_base = (size_t)b * T * D4;
        const int c2 = tid & 31;
        const int fg = tid >> 5;
        #pragma unroll
        for (int k = 0; k < FPB / 8; ++k) {
            const int lf = fg + (k << 3);
            const size_t xrow = x_base + (size_t)s_tok[lf] * D4;
            const size_t orow = out_base + (size_t)lf * D4;
            #pragma unroll
            for (int j = 0; j < 3; ++j) {
                const int c = c2 + (j << 5);
                __builtin_nontemporal_store(x[xrow + c], &out4[orow + c]);
            }
        }
    }
}

extern "C" void kernel_launch(void* const* d_in, const int* in_sizes, int n_in,
                              void* d_out, int out_size, void* d_ws, size_t ws_size,
                              hipStream_t stream) {
    const f32x4* x   = (const f32x4*)d_in[0];
    const int*   dur = (const int*)d_in[1];
    float* outf = (float*)d_out;
    float* mel  = outf + (size_t)B * ML * D;   // mel_pos region, float values

    dim3 grid(B * CHUNKS);    // 2048 blocks
    dim3 block(NT);
    lr_kernel<<<grid, block, 0, stream>>>(x, dur, (f32x4*)outf, mel);
}